// Round 5
// baseline (343.030 us; speedup 1.0000x reference)
//
#include <hip/hip_runtime.h>
#include <hip/hip_bf16.h>

#define B_ 8
#define N_ 256
#define H_ 128
#define E_ 32

typedef __bf16 bf16x8 __attribute__((ext_vector_type(8)));
typedef float f32x4 __attribute__((ext_vector_type(4)));

// round-to-nearest-even fp32 -> bf16
static __device__ __forceinline__ __bf16 f2bf(float f) {
    union { float f; unsigned int u; } a;
    a.f = f;
    const unsigned int r = a.u + 0x7FFFu + ((a.u >> 16) & 1u);
    union { unsigned short s; __bf16 b; } o;
    o.s = (unsigned short)(r >> 16);
    return o.b;
}

// Fused kernel, 2 graph-nodes i per WG processed SEQUENTIALLY (grid 1024).
//   h[i,:] = x[b,i,:] + sum_j adj[b,i,j]*relu(x[b,j,:] + e[b,i,j,:]@We + be)
//   out[i,:] = relu(h@W1+b1)@W2 + b2
//
// Register-pressure history (the governing constraint on this chip):
//   r1 (256,4)->64 arch regs, spilled (284 MB scratch); r2 (256,3)->84,
//   spilled; r3 (256,2)->128, fit at ~100 live -> 78us but only 2 waves/SIMD
//   (latency-bound, all pipes <25%); r4 added pair-interleave state -> spilled
//   again (268 MB). gfx950 reserves launch-bounds-budget/2 for AGPRs, so
//   occupancy = 512 / budget waves/SIMD. This version moves the 32-reg We
//   fragment file into LDS (ds_read_b128 per use, 2-way bank alias = free)
//   dropping arch live set to ~70 => (256,3): 84 arch regs, 3 waves/SIMD.
__global__ __launch_bounds__(256, 3) void fused_kernel(
    const float* __restrict__ x, const int* __restrict__ adj,
    const float* __restrict__ e, const float* __restrict__ We,
    const float* __restrict__ be, const float* __restrict__ W1,
    const float* __restrict__ b1, const float* __restrict__ W2,
    const float* __restrict__ b2, float* __restrict__ out)
{
    __shared__ __bf16 wef[4 * 128 * 8];   // [quad][hcol][k8], 8 KB
    __shared__ float red[4][128];
    __shared__ float hvec[2][128];
    __shared__ float ts[2][256];
    __shared__ float part[2][256];

    const int tile = blockIdx.x;          // 1024 tiles of 2 i
    const int b    = tile >> 7;
    const int i0   = (tile & 127) << 1;
    const int tid  = threadIdx.x;
    const int w    = tid >> 6;
    const int lane = tid & 63;
    const int quad = lane >> 4;
    const int col  = lane & 15;

    // Stage We as per-lane MFMA B-fragments in LDS: fragment for (quad,hcol)
    // is 8 contiguous bf16 = one ds_read_b128 at consume time.
    for (int p = tid; p < 512; p += 256) {        // p = q*128 + hcol
        const int q = p >> 7, hcol = p & 127;
        bf16x8 t;
#pragma unroll
        for (int kk = 0; kk < 8; ++kk)
            t[kk] = f2bf(We[(q * 8 + kk) * H_ + hcol]);
        *(bf16x8*)&wef[p * 8] = t;
    }
    __syncthreads();

    // be fragment: 8 regs, resident for the whole kernel.
    float bef[8];
#pragma unroll
    for (int ht = 0; ht < 8; ++ht) bef[ht] = be[ht * 16 + col];

    const f32x4 zero4 = {0.0f, 0.0f, 0.0f, 0.0f};

#pragma unroll 1   // sequential i: keeps psum[8] (not [2][8]) live
    for (int ii = 0; ii < 2; ++ii) {
        const int i = i0 + ii;
        const size_t rowbase = (size_t)(b * N_ + i) * N_;

        float psum[8];
#pragma unroll
        for (int ht = 0; ht < 8; ++ht) psum[ht] = 0.0f;

#pragma unroll
        for (int c = 0; c < 4; ++c) {
            const int j0 = (c * 4 + w) * 16;
            const int jr = j0 + quad * 4;

            // adj mask, one int4 for this lane's 4 j-rows.
            const int4 av = *(const int4*)(adj + rowbase + jr);
            float adjf[4];
            adjf[0] = av.x ? 1.0f : 0.0f;
            adjf[1] = av.y ? 1.0f : 0.0f;
            adjf[2] = av.z ? 1.0f : 0.0f;
            adjf[3] = av.w ? 1.0f : 0.0f;

            // A fragment: e[b,i, j0+col, quad*8 .. +7] (wave union = 2 KiB)
            const float* ap = e + (rowbase + (size_t)(j0 + col)) * E_ + quad * 8;
            const float4 a0 = *(const float4*)ap;
            const float4 a1 = *(const float4*)(ap + 4);
            bf16x8 af;
            af[0] = f2bf(a0.x); af[1] = f2bf(a0.y); af[2] = f2bf(a0.z); af[3] = f2bf(a0.w);
            af[4] = f2bf(a1.x); af[5] = f2bf(a1.y); af[6] = f2bf(a1.z); af[7] = f2bf(a1.w);

            const float* xrow = x + ((size_t)(b * N_ + jr)) * H_ + col;

            // Two groups of 4 h-tiles (16 acc regs live per group); B-frags
            // pulled from LDS per use (frees 32 arch VGPRs vs r3).
#pragma unroll
            for (int g = 0; g < 2; ++g) {
                f32x4 acc[4];
#pragma unroll
                for (int t = 0; t < 4; ++t) {
                    const bf16x8 bwf =
                        *(const bf16x8*)&wef[(quad * 128 + (g * 4 + t) * 16 + col) * 8];
                    acc[t] = __builtin_amdgcn_mfma_f32_16x16x32_bf16(af, bwf, zero4, 0, 0, 0);
                }
#pragma unroll
                for (int r = 0; r < 4; ++r) {
                    const float* xr = xrow + (size_t)r * H_;
#pragma unroll
                    for (int t = 0; t < 4; ++t) {
                        const int ht = g * 4 + t;
                        const float v = acc[t][r] + xr[ht * 16] + bef[ht];
                        psum[ht] += adjf[r] * fmaxf(v, 0.0f);
                    }
                }
            }
        }

        // Quad reduce in-register, wave reduce via LDS; h = agg + x[b,i,:].
#pragma unroll
        for (int ht = 0; ht < 8; ++ht) {
            float v = psum[ht];
            v += __shfl_xor(v, 16);
            v += __shfl_xor(v, 32);
            if (lane < 16) red[w][ht * 16 + lane] = v;
        }
        __syncthreads();
        if (tid < 128) {
            const float aggv = red[0][tid] + red[1][tid] + red[2][tid] + red[3][tid];
            hvec[ii][tid] = aggv + x[((size_t)(b * N_ + i)) * H_ + tid];
        }
        __syncthreads();   // red reused next i
    }

    // ---- MLP (fp32), 2 rows share every weight load; W1/W2 are L2-hot
    // (384 KB broadcast across all WGs).
    // Layer 1: thread owns output column c = tid for both rows.
    {
        const int c = tid;
        float acc0 = 0.f, acc1 = 0.f;
        for (int k = 0; k < 128; k += 4) {
            const float w0 = W1[(k + 0) * 256 + c];
            const float w1 = W1[(k + 1) * 256 + c];
            const float w2 = W1[(k + 2) * 256 + c];
            const float w3 = W1[(k + 3) * 256 + c];
            const float4 h0 = *(const float4*)&hvec[0][k];
            const float4 h1 = *(const float4*)&hvec[1][k];
            acc0 += h0.x * w0 + h0.y * w1 + h0.z * w2 + h0.w * w3;
            acc1 += h1.x * w0 + h1.y * w1 + h1.z * w2 + h1.w * w3;
        }
        const float bb = b1[c];
        ts[0][c] = fmaxf(acc0 + bb, 0.0f);
        ts[1][c] = fmaxf(acc1 + bb, 0.0f);
    }
    __syncthreads();

    // Layer 2: two threads per column (k split 128/128), both rows each.
    {
        const int cc = tid & 127;
        const int kb = (tid >> 7) * 128;
        float acc0 = 0.f, acc1 = 0.f;
        for (int k = 0; k < 128; k += 4) {
            const float w0 = W2[(kb + k + 0) * 128 + cc];
            const float w1 = W2[(kb + k + 1) * 128 + cc];
            const float w2 = W2[(kb + k + 2) * 128 + cc];
            const float w3 = W2[(kb + k + 3) * 128 + cc];
            const float4 t0 = *(const float4*)&ts[0][kb + k];
            const float4 t1 = *(const float4*)&ts[1][kb + k];
            acc0 += t0.x * w0 + t0.y * w1 + t0.z * w2 + t0.w * w3;
            acc1 += t1.x * w0 + t1.y * w1 + t1.z * w2 + t1.w * w3;
        }
        part[0][tid] = acc0;
        part[1][tid] = acc1;
    }
    __syncthreads();
    {
        const int t = tid & 127;
        const int r = tid >> 7;
        out[((size_t)(b * N_ + i0 + r)) * H_ + t] =
            part[r][t] + part[r][t + 128] + b2[t];
    }
}

extern "C" void kernel_launch(void* const* d_in, const int* in_sizes, int n_in,
                              void* d_out, int out_size, void* d_ws, size_t ws_size,
                              hipStream_t stream) {
    const float* x   = (const float*)d_in[0];
    const int*   adj = (const int*)  d_in[1];
    const float* e   = (const float*)d_in[2];
    const float* We  = (const float*)d_in[3];
    const float* be  = (const float*)d_in[4];
    const float* W1  = (const float*)d_in[5];
    const float* b1  = (const float*)d_in[6];
    const float* W2  = (const float*)d_in[7];
    const float* b2  = (const float*)d_in[8];
    float* out = (float*)d_out;

    fused_kernel<<<dim3(B_ * N_ / 2), dim3(256), 0, stream>>>(
        x, adj, e, We, be, W1, b1, W2, b2, out);
}

// Round 6
// 169.071 us; speedup vs baseline: 2.0289x; 2.0289x over previous
//
#include <hip/hip_runtime.h>
#include <hip/hip_bf16.h>

#define B_ 8
#define N_ 256
#define H_ 128
#define E_ 32

typedef __bf16 bf16x8 __attribute__((ext_vector_type(8)));
typedef float f32x4 __attribute__((ext_vector_type(4)));

// round-to-nearest-even fp32 -> bf16
static __device__ __forceinline__ __bf16 f2bf(float f) {
    union { float f; unsigned int u; } a;
    a.f = f;
    const unsigned int r = a.u + 0x7FFFu + ((a.u >> 16) & 1u);
    union { unsigned short s; __bf16 b; } o;
    o.s = (unsigned short)(r >> 16);
    return o.b;
}

// Tiny precompute: xb[b,j,h] = x[b,j,h] + be[h].  Folds the bias add out of
// the hot epilogue (131k elements per WG) and frees 8 regs there.
__global__ __launch_bounds__(256) void xb_kernel(
    const float* __restrict__ x, const float* __restrict__ be,
    float* __restrict__ xb)
{
    const int idx = blockIdx.x * 256 + threadIdx.x;   // float4 index, 65536 total
    float4 v = ((const float4*)x)[idx];
    const float4 bv = ((const float4*)be)[idx & 31];  // 32 float4 per 128-row
    v.x += bv.x; v.y += bv.y; v.z += bv.z; v.w += bv.w;
    ((float4*)xb)[idx] = v;
}

// Fused kernel, one WG per (b,i)  (r3 structure: the only one measured
// spill-free; (256,2) -> 128 arch + 128 acc regs, 2 waves/SIMD).
//   h[:]   = x[b,i,:] + sum_j adj[b,i,j]*relu(xb[b,j,:] + e[b,i,j,:]@We)
//   out[:] = relu(h@W1+b1)@W2 + b2
//
// Register-pressure history (governing constraint): (256,4)/(256,3) configs
// spilled every time regardless of structure (r1,r2,r4,r5: 130-280 MB scratch
// traffic, 3x slowdown). Occupancy is pinned at 2 waves/SIMD; this round adds
// ILP instead: e/adj loads software-pipelined one j-chunk ahead (epilogue's
// ~500 VALU cycles cover the ~900-cycle HBM latency), xb precompute cuts the
// epilogue to 3 VALU/element. Net reg delta vs r3: -8 (bef) +12 (prefetch).
__global__ __launch_bounds__(256, 2) void fused_kernel(
    const float* __restrict__ x, const int* __restrict__ adj,
    const float* __restrict__ e, const float* __restrict__ We,
    const float* __restrict__ xb, const float* __restrict__ W1,
    const float* __restrict__ b1, const float* __restrict__ W2,
    const float* __restrict__ b2, float* __restrict__ out)
{
    __shared__ float red[4][128];
    __shared__ float hvec[128];
    __shared__ float ts[256];
    __shared__ float part[256];

    const int bi   = blockIdx.x;      // b*256 + i
    const int b    = bi >> 8;
    const int tid  = threadIdx.x;
    const int w    = tid >> 6;
    const int lane = tid & 63;
    const int quad = lane >> 4;
    const int col  = lane & 15;

    // Preload all of We as B-fragments (8 h-tiles x 8 bf16 = 32 VGPRs).
    bf16x8 bw[8];
#pragma unroll
    for (int ht = 0; ht < 8; ++ht)
#pragma unroll
        for (int kk = 0; kk < 8; ++kk)
            bw[ht][kk] = f2bf(We[(quad * 8 + kk) * H_ + ht * 16 + col]);

    float psum[8];
#pragma unroll
    for (int ht = 0; ht < 8; ++ht) psum[ht] = 0.0f;

    const size_t ebase   = (size_t)bi * (N_ * E_);
    const size_t adjbase = (size_t)bi * N_;
    const f32x4 zero4 = {0.0f, 0.0f, 0.0f, 0.0f};

    // Prefetch chunk 0 (e: two float4 = this lane's A-fragment; adj: int4).
    float4 a0, a1;
    int4   av;
    {
        const int j0 = w * 16;
        const float* ap = e + ebase + (size_t)(j0 + col) * E_ + quad * 8;
        a0 = *(const float4*)ap;
        a1 = *(const float4*)(ap + 4);
        av = *(const int4*)(adj + adjbase + j0 + quad * 4);
    }

#pragma unroll
    for (int c = 0; c < 4; ++c) {
        const int j0 = (c * 4 + w) * 16;
        const int jr = j0 + quad * 4;

        // Consume current prefetch into the A-fragment + mask.
        bf16x8 af;
        af[0] = f2bf(a0.x); af[1] = f2bf(a0.y); af[2] = f2bf(a0.z); af[3] = f2bf(a0.w);
        af[4] = f2bf(a1.x); af[5] = f2bf(a1.y); af[6] = f2bf(a1.z); af[7] = f2bf(a1.w);
        float adjf[4];
        adjf[0] = av.x ? 1.0f : 0.0f;
        adjf[1] = av.y ? 1.0f : 0.0f;
        adjf[2] = av.z ? 1.0f : 0.0f;
        adjf[3] = av.w ? 1.0f : 0.0f;

        // Issue next chunk's loads NOW; the MFMA+epilogue below hides them.
        if (c < 3) {
            const int j0n = ((c + 1) * 4 + w) * 16;
            const float* apn = e + ebase + (size_t)(j0n + col) * E_ + quad * 8;
            a0 = *(const float4*)apn;
            a1 = *(const float4*)(apn + 4);
            av = *(const int4*)(adj + adjbase + j0n + quad * 4);
        }

        const float* xbrow = xb + ((size_t)(b * N_ + jr)) * H_ + col;

        // Two groups of 4 h-tiles (16 acc regs live per group).
#pragma unroll
        for (int g = 0; g < 2; ++g) {
            f32x4 acc[4];
#pragma unroll
            for (int t = 0; t < 4; ++t)
                acc[t] = __builtin_amdgcn_mfma_f32_16x16x32_bf16(af, bw[g * 4 + t], zero4, 0, 0, 0);
#pragma unroll
            for (int r = 0; r < 4; ++r) {
                const float* xr = xbrow + (size_t)r * H_;
#pragma unroll
                for (int t = 0; t < 4; ++t) {
                    const int ht = g * 4 + t;
                    const float v = acc[t][r] + xr[ht * 16];   // xb = x + be
                    psum[ht] += adjf[r] * fmaxf(v, 0.0f);
                }
            }
        }
    }

    // Quad reduce in-register, wave reduce via LDS; h = agg + x[b,i,:].
#pragma unroll
    for (int ht = 0; ht < 8; ++ht) {
        float v = psum[ht];
        v += __shfl_xor(v, 16);
        v += __shfl_xor(v, 32);
        if (lane < 16) red[w][ht * 16 + lane] = v;
    }
    __syncthreads();
    if (tid < 128) {
        const float aggv = red[0][tid] + red[1][tid] + red[2][tid] + red[3][tid];
        hvec[tid] = aggv + x[(size_t)bi * H_ + tid];
    }
    __syncthreads();

    // ---- MLP (fp32), weights stream from L2 (384 KB shared by all WGs).
    // Layer 1: thread tid owns output column tid.
    {
        const int c = tid;
        float a0m = 0.f, a1m = 0.f, a2m = 0.f, a3m = 0.f;
        for (int k = 0; k < 128; k += 4) {
            a0m += hvec[k + 0] * W1[(k + 0) * 256 + c];
            a1m += hvec[k + 1] * W1[(k + 1) * 256 + c];
            a2m += hvec[k + 2] * W1[(k + 2) * 256 + c];
            a3m += hvec[k + 3] * W1[(k + 3) * 256 + c];
        }
        ts[c] = fmaxf((a0m + a1m) + (a2m + a3m) + b1[c], 0.0f);
    }
    __syncthreads();

    // Layer 2: two threads per output column, k split 128/128.
    {
        const int c  = tid & 127;
        const int kb = (tid >> 7) * 128;
        float a0m = 0.f, a1m = 0.f, a2m = 0.f, a3m = 0.f;
        for (int k = 0; k < 128; k += 4) {
            a0m += ts[kb + k + 0] * W2[(kb + k + 0) * 128 + c];
            a1m += ts[kb + k + 1] * W2[(kb + k + 1) * 128 + c];
            a2m += ts[kb + k + 2] * W2[(kb + k + 2) * 128 + c];
            a3m += ts[kb + k + 3] * W2[(kb + k + 3) * 128 + c];
        }
        part[tid] = (a0m + a1m) + (a2m + a3m);
    }
    __syncthreads();
    if (tid < 128)
        out[(size_t)bi * H_ + tid] = part[tid] + part[tid + 128] + b2[tid];
}

extern "C" void kernel_launch(void* const* d_in, const int* in_sizes, int n_in,
                              void* d_out, int out_size, void* d_ws, size_t ws_size,
                              hipStream_t stream) {
    const float* x   = (const float*)d_in[0];
    const int*   adj = (const int*)  d_in[1];
    const float* e   = (const float*)d_in[2];
    const float* We  = (const float*)d_in[3];
    const float* be  = (const float*)d_in[4];
    const float* W1  = (const float*)d_in[5];
    const float* b1  = (const float*)d_in[6];
    const float* W2  = (const float*)d_in[7];
    const float* b2  = (const float*)d_in[8];
    float* out = (float*)d_out;
    float* xbw = (float*)d_ws;   // [B*N, H] fp32, 1 MiB

    xb_kernel<<<dim3(B_ * N_ * H_ / 1024), dim3(256), 0, stream>>>(x, be, xbw);
    fused_kernel<<<dim3(B_ * N_), dim3(256), 0, stream>>>(
        x, adj, e, We, xbw, W1, b1, W2, b2, out);
}

// Round 8
// 155.666 us; speedup vs baseline: 2.2036x; 1.0861x over previous
//
#include <hip/hip_runtime.h>
#include <hip/hip_bf16.h>

#define B_ 8
#define N_ 256
#define H_ 128
#define E_ 32

typedef __bf16 bf16x8 __attribute__((ext_vector_type(8)));
typedef __bf16 bf16x4 __attribute__((ext_vector_type(4)));
typedef float f32x4 __attribute__((ext_vector_type(4)));

// round-to-nearest-even fp32 -> bf16
static __device__ __forceinline__ __bf16 f2bf(float f) {
    union { float f; unsigned int u; } a;
    a.f = f;
    const unsigned int r = a.u + 0x7FFFu + ((a.u >> 16) & 1u);
    union { unsigned short s; __bf16 b; } o;
    o.s = (unsigned short)(r >> 16);
    return o.b;
}

// ws layout — r7 FAILED because xbT (B*H*N = 262144 elems) overlapped the
// weight regions (W1T_OFF was 65536). Now: xbT stored as bf16 so everything
// fits in 776 KiB < the 1 MiB proven available in r1/r2/r6.
//   xbT  : bf16, elem [0, 262144)            = bytes [0, 524288)
//   W1T  : f32,  float-offset [131072, 163840)
//   W2T  : f32,  float-offset [163840, 196608)
//   Webf : bf16, float-offset 196608, 4096 elems (8 KiB)
#define W1T_OFF  131072
#define W2T_OFF  163840
#define WEBF_OFF 196608

// Prep: (a) xbT[b,h,j] = bf16(x[b,j,h] + be[h]), (b) W1T/W2T transposes,
// (c) We packed as per-lane bf16 MFMA B-fragments (one dwordx4 per tile).
__global__ __launch_bounds__(256) void prep_kernel(
    const float* __restrict__ x, const float* __restrict__ be,
    const float* __restrict__ W1, const float* __restrict__ W2,
    const float* __restrict__ We, float* __restrict__ ws)
{
    const int blk = blockIdx.x;
    if (blk == 320) {               // (c) We fragments: [quad][h][kk] bf16
        __bf16* Webf = (__bf16*)(ws + WEBF_OFF);
        for (int q = threadIdx.x; q < 512; q += 256) {
            const int quad = q >> 7, h = q & 127;
            bf16x8 t;
#pragma unroll
            for (int kk = 0; kk < 8; ++kk)
                t[kk] = f2bf(We[(quad * 8 + kk) * H_ + h]);
            *(bf16x8*)&Webf[q * 8] = t;
        }
        return;
    }
    __shared__ float tile[32][33];
    const int tx = threadIdx.x & 31, ty = threadIdx.x >> 5;   // ty 0..7
    if (blk < 256) {                // (a) per-batch x transpose, bf16 out
        const int b = blk >> 5, t = blk & 31;
        const float* src = x + (size_t)b * N_ * H_;
        __bf16* dst = (__bf16*)ws + (size_t)b * H_ * N_;
        const int r0 = (t >> 2) * 32, c0 = (t & 3) * 32;      // j0, h0
#pragma unroll
        for (int p = 0; p < 4; ++p)
            tile[ty + p * 8][tx] =
                src[(size_t)(r0 + ty + p * 8) * H_ + c0 + tx] + be[c0 + tx];
        __syncthreads();
#pragma unroll
        for (int p = 0; p < 4; ++p)
            dst[(size_t)(c0 + ty + p * 8) * N_ + r0 + tx] = f2bf(tile[tx][ty + p * 8]);
        return;
    }
    // (b) weight transposes (float dst)
    const float* src; float* dst; int R, C, r0, c0;
    if (blk < 288) {                // W1: 128x256 -> 256x128
        const int t = blk - 256;
        src = W1; dst = ws + W1T_OFF;
        R = 128; C = 256; r0 = (t >> 3) * 32; c0 = (t & 7) * 32;
    } else {                        // W2: 256x128 -> 128x256
        const int t = blk - 288;
        src = W2; dst = ws + W2T_OFF;
        R = 256; C = 128; r0 = (t >> 2) * 32; c0 = (t & 3) * 32;
    }
#pragma unroll
    for (int p = 0; p < 4; ++p)
        tile[ty + p * 8][tx] = src[(size_t)(r0 + ty + p * 8) * C + c0 + tx];
    __syncthreads();
#pragma unroll
    for (int p = 0; p < 4; ++p)
        dst[(size_t)(c0 + ty + p * 8) * R + r0 + tx] = tile[tx][ty + p * 8];
}

// Aggregation: one WG per (b,i)  ((256,2): only spill-free config — r1/r2/
// r4/r5 all spilled 130-280 MB at higher occupancy).
//   h[b,i,:] = x[b,i,:] + sum_j adj*relu(xb[b,j,:] + e[b,i,j,:]@We)
// r6 diagnosis: load-ISSUE bound. This version: We as 8 dwordx4 fragment
// loads (pre-packed), epilogue via bf16 xbT as 8 dwordx2 loads/chunk.
// h written to d_out (scratch reuse); mlp_kernel overwrites it in place.
__global__ __launch_bounds__(256, 2) void agg_kernel(
    const int* __restrict__ adj, const float* __restrict__ e,
    const float* __restrict__ ws, const float* __restrict__ x,
    float* __restrict__ hout)
{
    __shared__ float red[4][128];
    const int bi   = blockIdx.x;      // b*256 + i
    const int b    = bi >> 8;
    const int tid  = threadIdx.x;
    const int w    = tid >> 6;
    const int lane = tid & 63;
    const int quad = lane >> 4;
    const int col  = lane & 15;

    // We B-fragments: 8 x dwordx4 from the pre-packed table.
    const __bf16* Webf = (const __bf16*)(ws + WEBF_OFF);
    bf16x8 bw[8];
#pragma unroll
    for (int ht = 0; ht < 8; ++ht)
        bw[ht] = *(const bf16x8*)&Webf[(quad * 128 + ht * 16 + col) * 8];

    float psum[8];
#pragma unroll
    for (int ht = 0; ht < 8; ++ht) psum[ht] = 0.0f;

    const size_t ebase   = (size_t)bi * (N_ * E_);
    const size_t adjbase = (size_t)bi * N_;
    const f32x4 zero4 = {0.0f, 0.0f, 0.0f, 0.0f};

    // Prefetch chunk 0 (e: this lane's A-fragment; adj: int4).
    float4 a0, a1;
    int4   av;
    {
        const int j0 = w * 16;
        const float* ap = e + ebase + (size_t)(j0 + col) * E_ + quad * 8;
        a0 = *(const float4*)ap;
        a1 = *(const float4*)(ap + 4);
        av = *(const int4*)(adj + adjbase + j0 + quad * 4);
    }

#pragma unroll
    for (int c = 0; c < 4; ++c) {
        const int j0 = (c * 4 + w) * 16;
        const int jr = j0 + quad * 4;

        bf16x8 af;
        af[0] = f2bf(a0.x); af[1] = f2bf(a0.y); af[2] = f2bf(a0.z); af[3] = f2bf(a0.w);
        af[4] = f2bf(a1.x); af[5] = f2bf(a1.y); af[6] = f2bf(a1.z); af[7] = f2bf(a1.w);
        float adjf[4];
        adjf[0] = av.x ? 1.0f : 0.0f;
        adjf[1] = av.y ? 1.0f : 0.0f;
        adjf[2] = av.z ? 1.0f : 0.0f;
        adjf[3] = av.w ? 1.0f : 0.0f;

        if (c < 3) {
            const int j0n = ((c + 1) * 4 + w) * 16;
            const float* apn = e + ebase + (size_t)(j0n + col) * E_ + quad * 8;
            a0 = *(const float4*)apn;
            a1 = *(const float4*)(apn + 4);
            av = *(const int4*)(adj + adjbase + j0n + quad * 4);
        }

        // xbT[b, h, j] (bf16): lane reads 4 consecutive j at fixed h per tile.
        const __bf16* xp = (const __bf16*)ws + (size_t)b * (H_ * N_) + col * N_ + jr;

#pragma unroll
        for (int g = 0; g < 2; ++g) {
            f32x4 acc[4];
#pragma unroll
            for (int t = 0; t < 4; ++t)
                acc[t] = __builtin_amdgcn_mfma_f32_16x16x32_bf16(af, bw[g * 4 + t], zero4, 0, 0, 0);
#pragma unroll
            for (int t = 0; t < 4; ++t) {
                const int ht = g * 4 + t;
                const bf16x4 xv = *(const bf16x4*)(xp + (size_t)ht * 16 * N_);
#pragma unroll
                for (int r = 0; r < 4; ++r)
                    psum[ht] += adjf[r] * fmaxf(acc[t][r] + (float)xv[r], 0.0f);
            }
        }
    }

    // Quad reduce in-register, wave reduce via LDS; h = agg + x[b,i,:].
#pragma unroll
    for (int ht = 0; ht < 8; ++ht) {
        float v = psum[ht];
        v += __shfl_xor(v, 16);
        v += __shfl_xor(v, 32);
        if (lane < 16) red[w][ht * 16 + lane] = v;
    }
    __syncthreads();
    if (tid < 128) {
        const float aggv = red[0][tid] + red[1][tid] + red[2][tid] + red[3][tid];
        hout[(size_t)bi * H_ + tid] = aggv + x[(size_t)bi * H_ + tid];
    }
}

// MLP: out = relu(h@W1+b1)@W2 + b2, fp32, 8 rows/WG x 256 WGs.
// Weight L2 traffic: 256 WG x 262 KB = 67 MB (was 537 MB inline in r6).
// All weight loads f32x4 via transposed W1T/W2T. Reads h from d_out,
// overwrites the same 8 rows.
__global__ __launch_bounds__(256) void mlp_kernel(
    const float* __restrict__ ws, const float* __restrict__ b1,
    const float* __restrict__ b2, float* __restrict__ hio)
{
    __shared__ float hs[8][128];
    __shared__ float ts[8][256];
    __shared__ float part[8][2][128];
    const int tid = threadIdx.x;
    const int r0  = blockIdx.x * 8;

    ((f32x4*)hs)[tid] = ((const f32x4*)(hio + (size_t)r0 * H_))[tid];
    __syncthreads();

    // Layer 1: thread owns column tid for all 8 rows; W1T row = 128 floats.
    {
        const float* wrow = ws + W1T_OFF + (size_t)tid * 128;
        float acc[8] = {0.f, 0.f, 0.f, 0.f, 0.f, 0.f, 0.f, 0.f};
        for (int k = 0; k < 128; k += 4) {
            const f32x4 wv = *(const f32x4*)&wrow[k];
#pragma unroll
            for (int r = 0; r < 8; ++r) {
                const f32x4 hv = *(const f32x4*)&hs[r][k];   // LDS broadcast
                acc[r] += hv[0] * wv[0] + hv[1] * wv[1] + hv[2] * wv[2] + hv[3] * wv[3];
            }
        }
        const float bb = b1[tid];
#pragma unroll
        for (int r = 0; r < 8; ++r) ts[r][tid] = fmaxf(acc[r] + bb, 0.0f);
    }
    __syncthreads();

    // Layer 2: two threads per column (k split 128/128); W2T row = 256 floats.
    {
        const int c  = tid & 127;
        const int kb = (tid >> 7) * 128;
        const float* wrow = ws + W2T_OFF + (size_t)c * 256 + kb;
        float acc[8] = {0.f, 0.f, 0.f, 0.f, 0.f, 0.f, 0.f, 0.f};
        for (int k = 0; k < 128; k += 4) {
            const f32x4 wv = *(const f32x4*)&wrow[k];
#pragma unroll
            for (int r = 0; r < 8; ++r) {
                const f32x4 tv = *(const f32x4*)&ts[r][kb + k];  // 2-way bcast
                acc[r] += tv[0] * wv[0] + tv[1] * wv[1] + tv[2] * wv[2] + tv[3] * wv[3];
            }
        }
#pragma unroll
        for (int r = 0; r < 8; ++r) part[r][tid >> 7][c] = acc[r];
    }
    __syncthreads();
#pragma unroll
    for (int idx = tid; idx < 1024; idx += 256) {
        const int r = idx >> 7, c = idx & 127;
        hio[(size_t)(r0 + r) * H_ + c] = part[r][0][c] + part[r][1][c] + b2[c];
    }
}

extern "C" void kernel_launch(void* const* d_in, const int* in_sizes, int n_in,
                              void* d_out, int out_size, void* d_ws, size_t ws_size,
                              hipStream_t stream) {
    const float* x   = (const float*)d_in[0];
    const int*   adj = (const int*)  d_in[1];
    const float* e   = (const float*)d_in[2];
    const float* We  = (const float*)d_in[3];
    const float* be  = (const float*)d_in[4];
    const float* W1  = (const float*)d_in[5];
    const float* b1  = (const float*)d_in[6];
    const float* W2  = (const float*)d_in[7];
    const float* b2  = (const float*)d_in[8];
    float* out = (float*)d_out;
    float* ws  = (float*)d_ws;   // 776 KiB used (xbT bf16 + W1T + W2T + Webf)

    prep_kernel<<<dim3(321), dim3(256), 0, stream>>>(x, be, W1, W2, We, ws);
    agg_kernel<<<dim3(B_ * N_), dim3(256), 0, stream>>>(adj, e, ws, x, out);
    mlp_kernel<<<dim3(B_ * N_ / 8), dim3(256), 0, stream>>>(ws, b1, b2, out);
}

// Round 9
// 155.172 us; speedup vs baseline: 2.2106x; 1.0032x over previous
//
#include <hip/hip_runtime.h>
#include <hip/hip_bf16.h>

#define B_ 8
#define N_ 256
#define H_ 128
#define E_ 32

typedef __bf16 bf16x8 __attribute__((ext_vector_type(8)));
typedef __bf16 bf16x4 __attribute__((ext_vector_type(4)));
typedef float f32x4 __attribute__((ext_vector_type(4)));

// round-to-nearest-even fp32 -> bf16
static __device__ __forceinline__ __bf16 f2bf(float f) {
    union { float f; unsigned int u; } a;
    a.f = f;
    const unsigned int r = a.u + 0x7FFFu + ((a.u >> 16) & 1u);
    union { unsigned short s; __bf16 b; } o;
    o.s = (unsigned short)(r >> 16);
    return o.b;
}

// ws layout (xbT stored bf16 so total = 776 KiB):
//   xbT  : bf16, elem [0, 262144)            = bytes [0, 524288)
//   W1T  : f32,  float-offset [131072, 163840)
//   W2T  : f32,  float-offset [163840, 196608)
//   Webf : bf16, float-offset 196608, 4096 elems (8 KiB)
#define W1T_OFF  131072
#define W2T_OFF  163840
#define WEBF_OFF 196608

// Prep: (a) xbT[b,h,j] = bf16(x[b,j,h] + be[h]), (b) W1T/W2T transposes,
// (c) We packed as per-lane bf16 MFMA B-fragments (one dwordx4 per tile).
__global__ __launch_bounds__(256) void prep_kernel(
    const float* __restrict__ x, const float* __restrict__ be,
    const float* __restrict__ W1, const float* __restrict__ W2,
    const float* __restrict__ We, float* __restrict__ ws)
{
    const int blk = blockIdx.x;
    if (blk == 320) {               // (c) We fragments: [quad][h][kk] bf16
        __bf16* Webf = (__bf16*)(ws + WEBF_OFF);
        for (int q = threadIdx.x; q < 512; q += 256) {
            const int quad = q >> 7, h = q & 127;
            bf16x8 t;
#pragma unroll
            for (int kk = 0; kk < 8; ++kk)
                t[kk] = f2bf(We[(quad * 8 + kk) * H_ + h]);
            *(bf16x8*)&Webf[q * 8] = t;
        }
        return;
    }
    __shared__ float tile[32][33];
    const int tx = threadIdx.x & 31, ty = threadIdx.x >> 5;   // ty 0..7
    if (blk < 256) {                // (a) per-batch x transpose, bf16 out
        const int b = blk >> 5, t = blk & 31;
        const float* src = x + (size_t)b * N_ * H_;
        __bf16* dst = (__bf16*)ws + (size_t)b * H_ * N_;
        const int r0 = (t >> 2) * 32, c0 = (t & 3) * 32;      // j0, h0
#pragma unroll
        for (int p = 0; p < 4; ++p)
            tile[ty + p * 8][tx] =
                src[(size_t)(r0 + ty + p * 8) * H_ + c0 + tx] + be[c0 + tx];
        __syncthreads();
#pragma unroll
        for (int p = 0; p < 4; ++p)
            dst[(size_t)(c0 + ty + p * 8) * N_ + r0 + tx] = f2bf(tile[tx][ty + p * 8]);
        return;
    }
    // (b) weight transposes (float dst)
    const float* src; float* dst; int R, C, r0, c0;
    if (blk < 288) {                // W1: 128x256 -> 256x128
        const int t = blk - 256;
        src = W1; dst = ws + W1T_OFF;
        R = 128; C = 256; r0 = (t >> 3) * 32; c0 = (t & 7) * 32;
    } else {                        // W2: 256x128 -> 128x256
        const int t = blk - 288;
        src = W2; dst = ws + W2T_OFF;
        R = 256; C = 128; r0 = (t >> 2) * 32; c0 = (t & 3) * 32;
    }
#pragma unroll
    for (int p = 0; p < 4; ++p)
        tile[ty + p * 8][tx] = src[(size_t)(r0 + ty + p * 8) * C + c0 + tx];
    __syncthreads();
#pragma unroll
    for (int p = 0; p < 4; ++p)
        dst[(size_t)(c0 + ty + p * 8) * R + r0 + tx] = tile[tx][ty + p * 8];
}

// Aggregation: one WG per (b,i)  ((256,2): only spill-free config — every
// higher-occupancy attempt spilled 130-280 MB scratch).
//   h[b,i,:] = x[b,i,:] + sum_j adj*relu(xb[b,j,:] + e[b,i,j,:]@We)
// r8 confirmed load-ISSUE bound -> 46us. r9 delta: the 8 xbT loads per chunk
// were issued in the epilogue right before use (~200cyc L2 latency exposed,
// x8 groups x4 chunks). Hoist them to the TOP of each chunk so the af-cvt +
// 8 MFMAs cover the latency; also deepens outstanding loads/wave ~3->11.
// Cost: +16 VGPR (xv[8] bf16x4) -> peak ~124 <= 128 cap.
__global__ __launch_bounds__(256, 2) void agg_kernel(
    const int* __restrict__ adj, const float* __restrict__ e,
    const float* __restrict__ ws, const float* __restrict__ x,
    float* __restrict__ hout)
{
    __shared__ float red[4][128];
    const int bi   = blockIdx.x;      // b*256 + i
    const int b    = bi >> 8;
    const int tid  = threadIdx.x;
    const int w    = tid >> 6;
    const int lane = tid & 63;
    const int quad = lane >> 4;
    const int col  = lane & 15;

    // We B-fragments: 8 x dwordx4 from the pre-packed table.
    const __bf16* Webf = (const __bf16*)(ws + WEBF_OFF);
    bf16x8 bw[8];
#pragma unroll
    for (int ht = 0; ht < 8; ++ht)
        bw[ht] = *(const bf16x8*)&Webf[(quad * 128 + ht * 16 + col) * 8];

    float psum[8];
#pragma unroll
    for (int ht = 0; ht < 8; ++ht) psum[ht] = 0.0f;

    const size_t ebase   = (size_t)bi * (N_ * E_);
    const size_t adjbase = (size_t)bi * N_;
    const __bf16* xbase  = (const __bf16*)ws + (size_t)b * (H_ * N_) + col * N_;
    const f32x4 zero4 = {0.0f, 0.0f, 0.0f, 0.0f};

    // Prefetch chunk 0 (e: this lane's A-fragment; adj: int4).
    float4 a0, a1;
    int4   av;
    {
        const int j0 = w * 16;
        const float* ap = e + ebase + (size_t)(j0 + col) * E_ + quad * 8;
        a0 = *(const float4*)ap;
        a1 = *(const float4*)(ap + 4);
        av = *(const int4*)(adj + adjbase + j0 + quad * 4);
    }

#pragma unroll
    for (int c = 0; c < 4; ++c) {
        const int j0 = (c * 4 + w) * 16;
        const int jr = j0 + quad * 4;

        // Hoisted xbT loads for THIS chunk: 8 independent dwordx2, issued
        // before the cvt+MFMA block so their L2 latency is covered.
        const __bf16* xp = xbase + jr;
        bf16x4 xv[8];
#pragma unroll
        for (int ht = 0; ht < 8; ++ht)
            xv[ht] = *(const bf16x4*)(xp + (size_t)ht * 16 * N_);

        bf16x8 af;
        af[0] = f2bf(a0.x); af[1] = f2bf(a0.y); af[2] = f2bf(a0.z); af[3] = f2bf(a0.w);
        af[4] = f2bf(a1.x); af[5] = f2bf(a1.y); af[6] = f2bf(a1.z); af[7] = f2bf(a1.w);
        float adjf[4];
        adjf[0] = av.x ? 1.0f : 0.0f;
        adjf[1] = av.y ? 1.0f : 0.0f;
        adjf[2] = av.z ? 1.0f : 0.0f;
        adjf[3] = av.w ? 1.0f : 0.0f;

        if (c < 3) {
            const int j0n = ((c + 1) * 4 + w) * 16;
            const float* apn = e + ebase + (size_t)(j0n + col) * E_ + quad * 8;
            a0 = *(const float4*)apn;
            a1 = *(const float4*)(apn + 4);
            av = *(const int4*)(adj + adjbase + j0n + quad * 4);
        }

#pragma unroll
        for (int g = 0; g < 2; ++g) {
            f32x4 acc[4];
#pragma unroll
            for (int t = 0; t < 4; ++t)
                acc[t] = __builtin_amdgcn_mfma_f32_16x16x32_bf16(af, bw[g * 4 + t], zero4, 0, 0, 0);
#pragma unroll
            for (int t = 0; t < 4; ++t) {
                const int ht = g * 4 + t;
#pragma unroll
                for (int r = 0; r < 4; ++r)
                    psum[ht] += adjf[r] * fmaxf(acc[t][r] + (float)xv[ht][r], 0.0f);
            }
        }
    }

    // Quad reduce in-register, wave reduce via LDS; h = agg + x[b,i,:].
#pragma unroll
    for (int ht = 0; ht < 8; ++ht) {
        float v = psum[ht];
        v += __shfl_xor(v, 16);
        v += __shfl_xor(v, 32);
        if (lane < 16) red[w][ht * 16 + lane] = v;
    }
    __syncthreads();
    if (tid < 128) {
        const float aggv = red[0][tid] + red[1][tid] + red[2][tid] + red[3][tid];
        hout[(size_t)bi * H_ + tid] = aggv + x[(size_t)bi * H_ + tid];
    }
}

// MLP: out = relu(h@W1+b1)@W2 + b2, fp32, 8 rows/WG x 256 WGs.
// Weight L2 traffic: 256 WG x 262 KB = 67 MB. All weight loads f32x4 via
// transposed W1T/W2T. Reads h from d_out, overwrites the same 8 rows.
__global__ __launch_bounds__(256) void mlp_kernel(
    const float* __restrict__ ws, const float* __restrict__ b1,
    const float* __restrict__ b2, float* __restrict__ hio)
{
    __shared__ float hs[8][128];
    __shared__ float ts[8][256];
    __shared__ float part[8][2][128];
    const int tid = threadIdx.x;
    const int r0  = blockIdx.x * 8;

    ((f32x4*)hs)[tid] = ((const f32x4*)(hio + (size_t)r0 * H_))[tid];
    __syncthreads();

    // Layer 1: thread owns column tid for all 8 rows; W1T row = 128 floats.
    {
        const float* wrow = ws + W1T_OFF + (size_t)tid * 128;
        float acc[8] = {0.f, 0.f, 0.f, 0.f, 0.f, 0.f, 0.f, 0.f};
        for (int k = 0; k < 128; k += 4) {
            const f32x4 wv = *(const f32x4*)&wrow[k];
#pragma unroll
            for (int r = 0; r < 8; ++r) {
                const f32x4 hv = *(const f32x4*)&hs[r][k];   // LDS broadcast
                acc[r] += hv[0] * wv[0] + hv[1] * wv[1] + hv[2] * wv[2] + hv[3] * wv[3];
            }
        }
        const float bb = b1[tid];
#pragma unroll
        for (int r = 0; r < 8; ++r) ts[r][tid] = fmaxf(acc[r] + bb, 0.0f);
    }
    __syncthreads();

    // Layer 2: two threads per column (k split 128/128); W2T row = 256 floats.
    {
        const int c  = tid & 127;
        const int kb = (tid >> 7) * 128;
        const float* wrow = ws + W2T_OFF + (size_t)c * 256 + kb;
        float acc[8] = {0.f, 0.f, 0.f, 0.f, 0.f, 0.f, 0.f, 0.f};
        for (int k = 0; k < 128; k += 4) {
            const f32x4 wv = *(const f32x4*)&wrow[k];
#pragma unroll
            for (int r = 0; r < 8; ++r) {
                const f32x4 tv = *(const f32x4*)&ts[r][kb + k];  // 2-way bcast
                acc[r] += tv[0] * wv[0] + tv[1] * wv[1] + tv[2] * wv[2] + tv[3] * wv[3];
            }
        }
#pragma unroll
        for (int r = 0; r < 8; ++r) part[r][tid >> 7][c] = acc[r];
    }
    __syncthreads();
#pragma unroll
    for (int idx = tid; idx < 1024; idx += 256) {
        const int r = idx >> 7, c = idx & 127;
        hio[(size_t)(r0 + r) * H_ + c] = part[r][0][c] + part[r][1][c] + b2[c];
    }
}

extern "C" void kernel_launch(void* const* d_in, const int* in_sizes, int n_in,
                              void* d_out, int out_size, void* d_ws, size_t ws_size,
                              hipStream_t stream) {
    const float* x   = (const float*)d_in[0];
    const int*   adj = (const int*)  d_in[1];
    const float* e   = (const float*)d_in[2];
    const float* We  = (const float*)d_in[3];
    const float* be  = (const float*)d_in[4];
    const float* W1  = (const float*)d_in[5];
    const float* b1  = (const float*)d_in[6];
    const float* W2  = (const float*)d_in[7];
    const float* b2  = (const float*)d_in[8];
    float* out = (float*)d_out;
    float* ws  = (float*)d_ws;   // 776 KiB used (xbT bf16 + W1T + W2T + Webf)

    prep_kernel<<<dim3(321), dim3(256), 0, stream>>>(x, be, W1, W2, We, ws);
    agg_kernel<<<dim3(B_ * N_), dim3(256), 0, stream>>>(adj, e, ws, x, out);
    mlp_kernel<<<dim3(B_ * N_ / 8), dim3(256), 0, stream>>>(ws, b1, b2, out);
}